// Round 11
// baseline (131.954 us; speedup 1.0000x reference)
//
#include <hip/hip_runtime.h>

#define N_TOTAL 32768
#define D_DIM   512
#define C_DIM   64
#define M_DIM   128
#define ROWS_B  64          // rows per block -> grid = 512 (2 blocks/CU)

typedef unsigned short u16;
typedef unsigned int   u32;
typedef unsigned long long u64;
typedef unsigned char  u8;
typedef float  f32x4   __attribute__((ext_vector_type(4)));
typedef short  short8v __attribute__((ext_vector_type(8)));

#define WAIT_VM(N) asm volatile("s_waitcnt vmcnt(" #N ")" ::: "memory")

__device__ __forceinline__ u32 f2bf_bits(float f) {
    u32 u = __float_as_uint(f);
    return (u + 0x7FFFu + ((u >> 16) & 1u)) >> 16;   // RNE
}

// coalesced global -> LDS direct copy, 16 B/lane (wave-uniform LDS base)
__device__ __forceinline__ void gload_lds16(const float* g, float* l) {
    __builtin_amdgcn_global_load_lds(
        (const __attribute__((address_space(1))) void*)g,
        (__attribute__((address_space(3))) void*)l, 16, 0, 0);
}

// ---------------------------------------------------------------------------
// Kernel 1 (unchanged, r4-verified): Lbf = L in MFMA-B-fragment order, bf16.
// Fragment (ct, ch): lane holds B[k][n], n = ct*16 + (lane&15),
// k = ch*32 + (lane>>4)*8 + i. Layout [ct][ch][lane][8]. 256 KB, L2-resident.
// ---------------------------------------------------------------------------
__global__ __launch_bounds__(256) void build_lbf(
    const float* __restrict__ L, u16* __restrict__ Lbf)
{
    int idx  = blockIdx.x * 256 + threadIdx.x;   // 16384 threads = 64 blocks
    int lane = idx & 63;
    int ch   = (idx >> 6) & 31;
    int ct   = idx >> 11;                        // 0..7
    int m  = ct * 16 + (lane & 15);
    int k0 = ch * 32 + ((lane >> 4) * 8);
    const float* src = L + (size_t)m * 1024 + k0;
    float4 a = *(const float4*)(src);
    float4 b = *(const float4*)(src + 4);
    u32 w0 = f2bf_bits(a.x) | (f2bf_bits(a.y) << 16);
    u32 w1 = f2bf_bits(a.z) | (f2bf_bits(a.w) << 16);
    u32 w2 = f2bf_bits(b.x) | (f2bf_bits(b.y) << 16);
    u32 w3 = f2bf_bits(b.z) | (f2bf_bits(b.w) << 16);
    *(uint4*)(Lbf + (size_t)idx * 8) = make_uint4(w0, w1, w2, w3);
}

// ---------------------------------------------------------------------------
// Kernel 2 (megakernel, 2-phase, register-threshold descent):
// 64 rows/block, 8 waves, grid 512 -> 2 blocks/CU = 16 waves/CU (4/SIMD).
// Codes phase: per-wave only (NO barriers): lane=class holds its 15 tree
// thresholds in REGISTERS (loaded once from global T) -> descent is a pure
// VALU cndmask tree, no dependent LDS chain. 4 chunks of 16 rows; wave owns
// rows 2wv,2wv+1 of each chunk (4 gload_lds16/chunk, dbuf, counted
// WAIT_VM(4) 1-deep prefetch — r6-verified pattern).
// Gemm phase: wave = col-tile ct=wv; 1 coalesced 1 KB B-load feeds 4 MFMAs
// (B-traffic 131 MB L2 total). A = one-hot synth from codes (r4-verified).
// C/D: col=lane&15, row=(lane>>4)*4+j (m89). h==0 -> bit 0 == argmax
// first-max tie rule (bit = (x - t > 0), matching reference sign()).
// sC stride 68: write banks 17*lane mod 32 (<=2-way, free), read 16 distinct
// dwords + cross-half 2-way (free). LDS = 64 + 4.25 = 68.25 KB.
// ---------------------------------------------------------------------------
__global__ __launch_bounds__(512, 4) void mega_kernel(
    const float* __restrict__ I,
    const float* __restrict__ T,
    const int* __restrict__ dims,
    const u16* __restrict__ Lbf,
    float* __restrict__ out)
{
    __shared__ float sI[2][16 * D_DIM];     // 64 KB: [buf][16 rows][512]
    __shared__ u8    sC[C_DIM * 68];        // 4.25 KB: [cls]{68}[l15*4 + rt]

    const int tid  = threadIdx.x;
    const int lane = tid & 63;              // class c in codes phase
    const int wv   = tid >> 6;              // 0..7
    const int rowBase = blockIdx.x * ROWS_B;

    // per-lane tree thresholds -> 15 registers (lane = class), L2-hot reads
    float tr[15];
    #pragma unroll
    for (int j = 0; j < 15; ++j) tr[j] = T[lane * 15 + j];

    // per-lane dim indices: one coalesced int4 (1 KB, L2-hot)
    const int4 dml = ((const int4*)dims)[lane];

    auto issue = [&](int t) {   // stage chunk t's rows 2wv,2wv+1 (4 KB, 4 loads)
        const float* src = I + (size_t)(rowBase + t * 16 + wv * 2) * D_DIM;
        float* dst = &sI[t & 1][(wv * 2) * D_DIM];
        #pragma unroll
        for (int i = 0; i < 4; ++i)
            gload_lds16(src + i * 256 + lane * 4, dst + i * 256);
    };

    u32 c4[2] = {0u, 0u};       // c4[rr] byte t = code(chunk t, row 2wv+rr)

    auto descend = [&](int t) {
        #pragma unroll
        for (int rr = 0; rr < 2; ++rr) {
            const float* v = &sI[t & 1][(wv * 2 + rr) * D_DIM];
            float x0 = v[dml.x], x1 = v[dml.y], x2 = v[dml.z], x3 = v[dml.w];
            // pure-VALU select tree (no dependent LDS): node thresholds
            bool b0 = (x0 - tr[0]) > 0.0f;
            float t1v = b0 ? tr[2] : tr[1];
            bool b1 = (x1 - t1v) > 0.0f;
            float t2v = b0 ? (b1 ? tr[6] : tr[5]) : (b1 ? tr[4] : tr[3]);
            bool b2 = (x2 - t2v) > 0.0f;
            float t3v = b0 ? (b1 ? (b2 ? tr[14] : tr[13]) : (b2 ? tr[12] : tr[11]))
                           : (b1 ? (b2 ? tr[10] : tr[9])  : (b2 ? tr[8]  : tr[7]));
            bool b3 = (x3 - t3v) > 0.0f;
            int k = (((((int)b0 << 1) | (int)b1) << 1 | (int)b2) << 1) | (int)b3;
            c4[rr] |= (u32)k << (8 * t);
        }
    };

    // ---- codes phase: barrier-free, counted-vmcnt 1-deep prefetch ----
    issue(0); issue(1);
    WAIT_VM(4);                 // T(15) + chunk0 retired; chunk1 in flight
    descend(0); issue(2);
    WAIT_VM(4);                 // chunk1 done; chunk2 in flight
    descend(1); issue(3);
    WAIT_VM(4);                 // chunk2 done; chunk3 in flight
    descend(2);
    WAIT_VM(0);                 // chunk3 done
    descend(3);

    // codes -> LDS: byte (l15*4 + rt) of class row = code(row rt*16+l15);
    // lane writes l15 = 2wv+rr as ONE dword (banks 17*lane mod 32, free)
    #pragma unroll
    for (int rr = 0; rr < 2; ++rr)
        *(u32*)(sC + lane * 68 + (wv * 2 + rr) * 4) = c4[rr];
    __syncthreads();            // sC complete, all waves

    // ---- gemm phase: wave = col-tile wv; 1 B-load -> 4 MFMAs ----
    const int l15     = lane & 15;
    const int clsLane = (lane >> 5) & 1;        // which class of the k-chunk
    const int kb      = ((lane >> 4) & 1) * 8;  // k-offset within the class

    f32x4 acc[4] = {};
    const u16* lbW = Lbf + ((size_t)(wv * 32) * 64 + lane) * 8;   // ct = wv

    #pragma unroll 4
    for (int ch = 0; ch < 32; ++ch) {
        union { uint4 u; short8v v; } b;
        b.u = *(const uint4*)(lbW + (size_t)ch * 64 * 8);
        const int cls = ch * 2 + clsLane;
        const u32 codes4 = *(const u32*)(sC + cls * 68 + l15 * 4);
        #pragma unroll
        for (int rt = 0; rt < 4; ++rt) {
            u32 cd = (codes4 >> (8 * rt)) & 0xFFu;
            u32 tt = cd - (u32)kb;              // one-hot slot if 0..7
            u64 sv = 0x3F80ull << ((tt & 3) * 16);
            union { u64 d[2]; short8v v; } a;
            a.d[0] = (tt < 4) ? sv : 0ull;
            a.d[1] = (tt >= 4 && tt < 8) ? sv : 0ull;
            acc[rt] = __builtin_amdgcn_mfma_f32_16x16x32_bf16(
                          a.v, b.v, acc[rt], 0, 0, 0);
        }
    }

    // ---- epilogue: D row = (lane>>4)*4 + j, col = lane&15 ----
    #pragma unroll
    for (int rt = 0; rt < 4; ++rt) {
        int r0 = rowBase + rt * 16 + ((lane >> 4) << 2);
        float* o = out + (size_t)r0 * M_DIM + wv * 16 + l15;
        o[0 * M_DIM] = acc[rt][0];
        o[1 * M_DIM] = acc[rt][1];
        o[2 * M_DIM] = acc[rt][2];
        o[3 * M_DIM] = acc[rt][3];
    }
}

extern "C" void kernel_launch(void* const* d_in, const int* in_sizes, int n_in,
                              void* d_out, int out_size, void* d_ws, size_t ws_size,
                              hipStream_t stream) {
    // inputs: I(0) T(1) L(2) S(3) B(4) dims(5) temp(6) — fp32, dims int32
    const float* I    = (const float*)d_in[0];
    const float* T    = (const float*)d_in[1];
    const float* L    = (const float*)d_in[2];
    const int*   dims = (const int*)d_in[5];

    u16* Lbf = (u16*)d_ws;                      // 256 KB, fragment-ordered

    hipLaunchKernelGGL(build_lbf, dim3(64), dim3(256), 0, stream, L, Lbf);
    hipLaunchKernelGGL(mega_kernel, dim3(N_TOTAL / ROWS_B), dim3(512), 0, stream,
                       I, T, dims, Lbf, (float*)d_out);
}

// Round 12
// 124.971 us; speedup vs baseline: 1.0559x; 1.0559x over previous
//
#include <hip/hip_runtime.h>

#define N_TOTAL 32768
#define D_DIM   512
#define C_DIM   64
#define M_DIM   128
#define ROWS_B  64          // rows per block (grid = 512)

typedef unsigned short u16;
typedef unsigned int   u32;
typedef unsigned long long u64;
typedef unsigned char  u8;
typedef float  f32x4   __attribute__((ext_vector_type(4)));
typedef short  short8v __attribute__((ext_vector_type(8)));

#define WAIT_VM(N) asm volatile("s_waitcnt vmcnt(" #N ")" ::: "memory")

__device__ __forceinline__ u32 f2bf_bits(float f) {
    u32 u = __float_as_uint(f);
    return (u + 0x7FFFu + ((u >> 16) & 1u)) >> 16;   // RNE
}

// coalesced global -> LDS direct copy, 16 B/lane (wave-uniform LDS base)
__device__ __forceinline__ void gload_lds16(const float* g, float* l) {
    __builtin_amdgcn_global_load_lds(
        (const __attribute__((address_space(1))) void*)g,
        (__attribute__((address_space(3))) void*)l, 16, 0, 0);
}

// ---------------------------------------------------------------------------
// Kernel 1 (unchanged, r4-verified): Lbf = L in MFMA-B-fragment order, bf16.
// Fragment (ct, ch): lane holds B[k][n], n = ct*16 + (lane&15),
// k = ch*32 + (lane>>4)*8 + i. Layout [ct][ch][lane][8] -> 1 KB coalesced
// wave reads in the gemm. 256 KB, L2-resident.
// ---------------------------------------------------------------------------
__global__ __launch_bounds__(256) void build_lbf(
    const float* __restrict__ L, u16* __restrict__ Lbf)
{
    int idx  = blockIdx.x * 256 + threadIdx.x;   // 16384 threads = 64 blocks
    int lane = idx & 63;
    int ch   = (idx >> 6) & 31;
    int ct   = idx >> 11;                        // 0..7
    int m  = ct * 16 + (lane & 15);
    int k0 = ch * 32 + ((lane >> 4) * 8);
    const float* src = L + (size_t)m * 1024 + k0;
    float4 a = *(const float4*)(src);
    float4 b = *(const float4*)(src + 4);
    u32 w0 = f2bf_bits(a.x) | (f2bf_bits(a.y) << 16);
    u32 w1 = f2bf_bits(a.z) | (f2bf_bits(a.w) << 16);
    u32 w2 = f2bf_bits(b.x) | (f2bf_bits(b.y) << 16);
    u32 w3 = f2bf_bits(b.z) | (f2bf_bits(b.w) << 16);
    *(uint4*)(Lbf + (size_t)idx * 8) = make_uint4(w0, w1, w2, w3);
}

// ---------------------------------------------------------------------------
// Kernel 2: the r6 117.7-us winner with ONE change — thresholds in VGPRs.
// 64 rows/block, 4 waves, 256 threads, grid 512 (2 blocks/CU).
// Codes phase (barrier-free now): 4 chunks of 16 rows; wave stages its own
// 4 rows/chunk (8 x gload_lds16, dbuf) with counted WAIT_VM(8) 1-ahead
// prefetch (r6-verified). Descent = pure-VALU select tree on tr[15] regs
// (r11-verified formulas) — no dependent LDS chain, no sT, no prologue
// barrier. Codes accumulate in regs; one conflict-free write phase (sC2
// stride 68, banks 17*lane mod 32 = 2-way free), single __syncthreads.
// Gemm + epilogue: byte-identical to r6 (one-hot A synth, Lbf frags, C/D
// col=lane&15 row=(lane>>4)*4+j). h==0 -> bit 0 == argmax first-max tie.
// LDS = 64 + 4.25 = 68.25 KB.
// ---------------------------------------------------------------------------
__global__ __launch_bounds__(256, 2) void mega_kernel(
    const float* __restrict__ I,
    const float* __restrict__ T,
    const int* __restrict__ dims,
    const u16* __restrict__ Lbf,
    float* __restrict__ out)
{
    __shared__ float sI[2 * 16 * D_DIM];    // 64 KB dbuf, wave wv -> +4wv*512
    __shared__ u8    sC2[C_DIM * 68];       // 4.25 KB: [cls]{68}[l15*4 + rt]

    const int tid  = threadIdx.x;
    const int lane = tid & 63;              // class c in codes phase
    const int wv   = tid >> 6;
    const int rowBase = blockIdx.x * ROWS_B;

    // per-lane thresholds (lane = class) + dim indices, issued FIRST so the
    // first WAIT_VM(8) retires them together with chunk 0 (16 vmem items)
    float tr[15];
    #pragma unroll
    for (int j = 0; j < 15; ++j) tr[j] = T[lane * 15 + j];
    const int4 dml = ((const int4*)dims)[lane];

    auto issue = [&](int ci, int buf) {     // stage this wave's 4 rows (8 KB)
        const float* src = I + (size_t)(rowBase + ci * 16 + wv * 4) * D_DIM;
        float* dst = sI + buf * 16 * D_DIM + wv * 4 * D_DIM;
        #pragma unroll
        for (int i = 0; i < 8; ++i)
            gload_lds16(src + i * 256 + lane * 4, dst + i * 256);
    };

    u32 c4[4] = {0u, 0u, 0u, 0u};   // c4[rr] byte ci = code(chunk ci, row wv*4+rr)

    auto descend = [&](int buf, int ci) {
        #pragma unroll
        for (int rr = 0; rr < 4; ++rr) {
            const float* v = sI + buf * 16 * D_DIM + (wv * 4 + rr) * D_DIM;
            float x0 = v[dml.x], x1 = v[dml.y], x2 = v[dml.z], x3 = v[dml.w];
            // pure-VALU select tree (r11-verified): bit = (x - t_node) > 0
            bool b0 = (x0 - tr[0]) > 0.0f;
            float t1v = b0 ? tr[2] : tr[1];
            bool b1 = (x1 - t1v) > 0.0f;
            float t2v = b0 ? (b1 ? tr[6] : tr[5]) : (b1 ? tr[4] : tr[3]);
            bool b2 = (x2 - t2v) > 0.0f;
            float t3v = b0 ? (b1 ? (b2 ? tr[14] : tr[13]) : (b2 ? tr[12] : tr[11]))
                           : (b1 ? (b2 ? tr[10] : tr[9])  : (b2 ? tr[8]  : tr[7]));
            bool b3 = (x3 - t3v) > 0.0f;
            int k = (((((int)b0 << 1) | (int)b1) << 1 | (int)b2) << 1) | (int)b3;
            c4[rr] |= (u32)k << (8 * ci);
        }
    };

    // ---- codes phase: r6-verified counted-vmcnt pipeline, barrier-free ----
    issue(0, 0);                    // + tr/dml already issued: 24 items
    issue(1, 1);                    // 32 outstanding
    WAIT_VM(8);                     // tr, dml, chunk 0 done; chunk 1 in flight
    descend(0, 0);
    issue(2, 0);                    // buf0 (chunk 0) consumed
    WAIT_VM(8);                     // chunk 1 done, chunk 2 in flight
    descend(1, 1);
    issue(3, 1);
    WAIT_VM(8);                     // chunk 2 done, chunk 3 in flight
    descend(0, 2);
    WAIT_VM(0);                     // chunk 3 done
    descend(1, 3);

    // one conflict-free code-write phase: 4 x ds_write_b32 per lane
    #pragma unroll
    for (int rr = 0; rr < 4; ++rr)
        *(u32*)(sC2 + lane * 68 + (wv * 4 + rr) * 4) = c4[rr];
    __syncthreads();                // sC2 complete, all waves

    // ---- gemm phase (byte-identical to r6) ----
    const int l15     = lane & 15;
    const int clsLane = (lane >> 5) & 1;        // which class of the k-chunk
    const int kb      = ((lane >> 4) & 1) * 8;  // k-offset within the class

    f32x4 acc[4][2] = {};

    const u16* lb0 = Lbf + ((size_t)(wv * 2 + 0) * 32 * 64 + lane) * 8;
    const u16* lb1 = Lbf + ((size_t)(wv * 2 + 1) * 32 * 64 + lane) * 8;

    #pragma unroll 4
    for (int ch = 0; ch < 32; ++ch) {
        union { uint4 u; short8v v; } b0, b1;
        b0.u = *(const uint4*)(lb0 + (size_t)ch * 64 * 8);
        b1.u = *(const uint4*)(lb1 + (size_t)ch * 64 * 8);
        const int cls = ch * 2 + clsLane;
        const u32 codes4 = *(const u32*)(sC2 + cls * 68 + l15 * 4);
        #pragma unroll
        for (int rt = 0; rt < 4; ++rt) {
            u32 cd = (codes4 >> (8 * rt)) & 0xFFu;
            u32 tt = cd - (u32)kb;              // one-hot slot if 0..7
            u64 sv = 0x3F80ull << ((tt & 3) * 16);
            union { u64 d[2]; short8v v; } a;
            a.d[0] = (tt < 4) ? sv : 0ull;
            a.d[1] = (tt >= 4 && tt < 8) ? sv : 0ull;
            acc[rt][0] = __builtin_amdgcn_mfma_f32_16x16x32_bf16(
                             a.v, b0.v, acc[rt][0], 0, 0, 0);
            acc[rt][1] = __builtin_amdgcn_mfma_f32_16x16x32_bf16(
                             a.v, b1.v, acc[rt][1], 0, 0, 0);
        }
    }

    // ---- epilogue (byte-identical to r6) ----
    #pragma unroll
    for (int rt = 0; rt < 4; ++rt) {
        #pragma unroll
        for (int cj = 0; cj < 2; ++cj) {
            int col = (wv * 2 + cj) * 16 + l15;
            int r0  = rowBase + rt * 16 + ((lane >> 4) << 2);
            float* o = out + (size_t)r0 * M_DIM + col;
            o[0 * M_DIM] = acc[rt][cj][0];
            o[1 * M_DIM] = acc[rt][cj][1];
            o[2 * M_DIM] = acc[rt][cj][2];
            o[3 * M_DIM] = acc[rt][cj][3];
        }
    }
}

extern "C" void kernel_launch(void* const* d_in, const int* in_sizes, int n_in,
                              void* d_out, int out_size, void* d_ws, size_t ws_size,
                              hipStream_t stream) {
    // inputs: I(0) T(1) L(2) S(3) B(4) dims(5) temp(6) — fp32, dims int32
    const float* I    = (const float*)d_in[0];
    const float* T    = (const float*)d_in[1];
    const float* L    = (const float*)d_in[2];
    const int*   dims = (const int*)d_in[5];

    u16* Lbf = (u16*)d_ws;                      // 256 KB, fragment-ordered

    hipLaunchKernelGGL(build_lbf, dim3(64), dim3(256), 0, stream, L, Lbf);
    hipLaunchKernelGGL(mega_kernel, dim3(N_TOTAL / ROWS_B), dim3(256), 0, stream,
                       I, T, dims, Lbf, (float*)d_out);
}

// Round 13
// 117.048 us; speedup vs baseline: 1.1274x; 1.0677x over previous
//
#include <hip/hip_runtime.h>

#define N_TOTAL 32768
#define D_DIM   512
#define C_DIM   64
#define K_DIM   16
#define M_DIM   128
#define NODES_  15

typedef unsigned short u16;
typedef unsigned int   u32;
typedef unsigned long long u64;
typedef unsigned char  u8;
typedef float  f32x4   __attribute__((ext_vector_type(4)));
typedef short  short8v __attribute__((ext_vector_type(8)));

#define WAIT_VM(N) asm volatile("s_waitcnt vmcnt(" #N ")" ::: "memory")

__device__ __forceinline__ u32 f2bf_bits(float f) {
    u32 u = __float_as_uint(f);
    return (u + 0x7FFFu + ((u >> 16) & 1u)) >> 16;   // RNE
}

// coalesced global -> LDS direct copy, 16 B/lane (wave-uniform LDS base)
__device__ __forceinline__ void gload_lds16(const float* g, float* l) {
    __builtin_amdgcn_global_load_lds(
        (const __attribute__((address_space(1))) void*)g,
        (__attribute__((address_space(3))) void*)l, 16, 0, 0);
}

// ---------------------------------------------------------------------------
// Kernel 1 (r4-verified): Lbf = L in MFMA-B-fragment order, bf16.
// Fragment (ct, ch): lane holds B[k][n], n = ct*16 + (lane&15),
// k = ch*32 + (lane>>4)*8 + i. Layout [ct][ch][lane][8] -> 1 KB coalesced
// wave reads in the gemm. 256 KB, L2-resident.
// ---------------------------------------------------------------------------
__global__ __launch_bounds__(256) void build_lbf(
    const float* __restrict__ L, u16* __restrict__ Lbf)
{
    int idx  = blockIdx.x * 256 + threadIdx.x;   // 16384 threads = 64 blocks
    int lane = idx & 63;
    int ch   = (idx >> 6) & 31;
    int ct   = idx >> 11;                        // 0..7
    int m  = ct * 16 + (lane & 15);
    int k0 = ch * 32 + ((lane >> 4) * 8);
    const float* src = L + (size_t)m * 1024 + k0;
    float4 a = *(const float4*)(src);
    float4 b = *(const float4*)(src + 4);
    u32 w0 = f2bf_bits(a.x) | (f2bf_bits(a.y) << 16);
    u32 w1 = f2bf_bits(a.z) | (f2bf_bits(a.w) << 16);
    u32 w2 = f2bf_bits(b.x) | (f2bf_bits(b.y) << 16);
    u32 w3 = f2bf_bits(b.z) | (f2bf_bits(b.w) << 16);
    *(uint4*)(Lbf + (size_t)idx * 8) = make_uint4(w0, w1, w2, w3);
}

// ---------------------------------------------------------------------------
// Kernel 2 (megakernel — the measured session optimum, 117.7 us total):
// 64 rows/block, 4 waves, grid 512. Codes phase: 4 chunks of 16 rows,
// double-buffered per-wave sI regions; chunk ci+1's 8 gload_lds16 issued
// BEFORE the counted WAIT_VM(8) on chunk ci (loads in flight through every
// descent window). Codes accumulate in registers; one conflict-free write
// phase (sC2 stride 68 -> banks 17*lane mod 32, 2-way = free).
// Gemm phase: wave = 4 row-tiles x 2 col-tiles; A = synthesized one-hot
// from 4-bit code; B = coalesced 1 KB Lbf fragment loads (L2).
// C/D: col=lane&15, row=(lane>>4)*4+j (m89-verified).
// h==0 -> bit 0 == argmax first-max tie rule. LDS = 64+3.75+4.25 = 72 KB.
// ---------------------------------------------------------------------------
__global__ __launch_bounds__(256, 2) void mega_kernel(
    const float* __restrict__ I,
    const float* __restrict__ T,
    const int* __restrict__ dims,
    const u16* __restrict__ Lbf,
    float* __restrict__ out)
{
    __shared__ float sI[2 * 16 * D_DIM];    // 64 KB dbuf, wave wv -> +4wv*512
    __shared__ float sT[C_DIM * NODES_];    // 3.75 KB
    __shared__ u8    sC2[C_DIM * 68];       // 4.25 KB: [cls]{68}[l15*4 + rt]

    const int tid  = threadIdx.x;
    const int lane = tid & 63;              // class c in codes phase
    const int wv   = tid >> 6;
    const int rowBase = blockIdx.x * 64;

    // per-lane dim indices: one coalesced int4 (1 KB, L2-hot)
    const int4 dml = ((const int4*)dims)[lane];

    auto issue = [&](int ci, int buf) {
        const float* src = I + (size_t)(rowBase + ci * 16 + wv * 4) * D_DIM;
        float* dst = sI + buf * 16 * D_DIM + wv * 4 * D_DIM;
        #pragma unroll
        for (int i = 0; i < 8; ++i)
            gload_lds16(src + i * 256 + lane * 4, dst + i * 256);
    };

    u32 c4[4] = {0u, 0u, 0u, 0u};   // c4[rr] byte ci = code(chunk ci, row wv*4+rr)
    const float* tc = sT + lane * NODES_;

    auto descend = [&](int buf, int ci) {
        #pragma unroll
        for (int rr = 0; rr < 4; ++rr) {
            const float* v = sI + buf * 16 * D_DIM + (wv * 4 + rr) * D_DIM;
            float x0 = v[dml.x], x1 = v[dml.y], x2 = v[dml.z], x3 = v[dml.w];
            int node = 0, k = 0;
            int b0 = (x0 - tc[0] > 0.0f) ? 1 : 0;
            k = b0; node = 1 + b0;
            int b1 = (x1 - tc[node] > 0.0f) ? 1 : 0;
            k = (k << 1) | b1; node = (node << 1) + 1 + b1;
            int b2 = (x2 - tc[node] > 0.0f) ? 1 : 0;
            k = (k << 1) | b2; node = (node << 1) + 1 + b2;
            int b3 = (x3 - tc[node] > 0.0f) ? 1 : 0;
            k = (k << 1) | b3;
            c4[rr] |= (u32)k << (8 * ci);
        }
    };

    // prologue: chunk 0 staged under the sT fill; barrier drains it
    issue(0, 0);
    for (int j = tid; j < C_DIM * NODES_; j += 256) sT[j] = T[j];
    __syncthreads();                // sT ready, chunk-0 resident
    issue(1, 1);                    // chunk 1 in flight across descent 0

    descend(0, 0);
    issue(2, 0);                    // buf0 reads (chunk 0) already consumed
    WAIT_VM(8);                     // chunk 1 done, chunk 2 in flight
    descend(1, 1);
    issue(3, 1);
    WAIT_VM(8);                     // chunk 2 done, chunk 3 in flight
    descend(0, 2);
    WAIT_VM(0);                     // chunk 3 done
    descend(1, 3);

    // one conflict-free code-write phase: 4 x ds_write_b32 per lane
    #pragma unroll
    for (int rr = 0; rr < 4; ++rr)
        *(u32*)(sC2 + lane * 68 + (wv * 4 + rr) * 4) = c4[rr];
    __syncthreads();                // sC2 complete, all waves

    // ---- gemm phase ----
    const int l15     = lane & 15;
    const int clsLane = (lane >> 5) & 1;        // which class of the k-chunk
    const int kb      = ((lane >> 4) & 1) * 8;  // k-offset within the class

    f32x4 acc[4][2] = {};

    const u16* lb0 = Lbf + ((size_t)(wv * 2 + 0) * 32 * 64 + lane) * 8;
    const u16* lb1 = Lbf + ((size_t)(wv * 2 + 1) * 32 * 64 + lane) * 8;

    #pragma unroll 4
    for (int ch = 0; ch < 32; ++ch) {
        union { uint4 u; short8v v; } b0, b1;
        b0.u = *(const uint4*)(lb0 + (size_t)ch * 64 * 8);
        b1.u = *(const uint4*)(lb1 + (size_t)ch * 64 * 8);
        const int cls = ch * 2 + clsLane;
        // all 4 row-tiles' codes for (cls, l15): one <=2-way ds_read_b32
        const u32 codes4 = *(const u32*)(sC2 + cls * 68 + l15 * 4);
        #pragma unroll
        for (int rt = 0; rt < 4; ++rt) {
            u32 cd = (codes4 >> (8 * rt)) & 0xFFu;
            u32 tt = cd - (u32)kb;              // one-hot slot if 0..7
            u64 sv = 0x3F80ull << ((tt & 3) * 16);
            union { u64 d[2]; short8v v; } a;
            a.d[0] = (tt < 4) ? sv : 0ull;
            a.d[1] = (tt >= 4 && tt < 8) ? sv : 0ull;
            acc[rt][0] = __builtin_amdgcn_mfma_f32_16x16x32_bf16(
                             a.v, b0.v, acc[rt][0], 0, 0, 0);
            acc[rt][1] = __builtin_amdgcn_mfma_f32_16x16x32_bf16(
                             a.v, b1.v, acc[rt][1], 0, 0, 0);
        }
    }

    // epilogue: D row = (lane>>4)*4 + j, col = lane&15 (within 16x16 tile)
    #pragma unroll
    for (int rt = 0; rt < 4; ++rt) {
        #pragma unroll
        for (int cj = 0; cj < 2; ++cj) {
            int col = (wv * 2 + cj) * 16 + l15;
            int r0  = rowBase + rt * 16 + ((lane >> 4) << 2);
            float* o = out + (size_t)r0 * M_DIM + col;
            o[0 * M_DIM] = acc[rt][cj][0];
            o[1 * M_DIM] = acc[rt][cj][1];
            o[2 * M_DIM] = acc[rt][cj][2];
            o[3 * M_DIM] = acc[rt][cj][3];
        }
    }
}

extern "C" void kernel_launch(void* const* d_in, const int* in_sizes, int n_in,
                              void* d_out, int out_size, void* d_ws, size_t ws_size,
                              hipStream_t stream) {
    // inputs: I(0) T(1) L(2) S(3) B(4) dims(5) temp(6) — fp32, dims int32
    const float* I    = (const float*)d_in[0];
    const float* T    = (const float*)d_in[1];
    const float* L    = (const float*)d_in[2];
    const int*   dims = (const int*)d_in[5];

    u16* Lbf = (u16*)d_ws;                      // 256 KB, fragment-ordered

    hipLaunchKernelGGL(build_lbf, dim3(64), dim3(256), 0, stream, L, Lbf);
    hipLaunchKernelGGL(mega_kernel, dim3(N_TOTAL / 64), dim3(256), 0, stream,
                       I, T, dims, Lbf, (float*)d_out);
}